// Round 3
// baseline (1153.354 us; speedup 1.0000x reference)
//
#include <hip/hip_runtime.h>

// Problem: bs=8, seq=16, hw=32*32=1024, ck=256, cv=3, steps=seq-1=15
// R8 design: R6 structure (verified 764us) with latency attacked directly.
//  - attn_step: 1024 thr = 16 waves = 4 waves/SIMD (was 8 waves = 2/SIMD).
//    Wave = (p-chunk, q-half): Bq shrinks to 32 VGPR -> no spill at the
//    forced 4-wave/SIMD VGPR cap (128); doubled latency hiding.
//  - scan_state: ILP-4 EMA chains, all 4 chains' loads issued before EMAs
//    (256B/lane in flight, was 64B) -> MLP-bound latency fixed.
#define BS 8
#define SEQ 16
#define HW 1024
#define CK 256
#define CV 3
#define STEPS 15

#define SKP 264   // padded fp16 LDS row stride (256+8)

typedef unsigned short u16;
typedef _Float16 half8 __attribute__((ext_vector_type(8)));  // MFMA A/B frag
typedef float floatx4 __attribute__((ext_vector_type(4)));   // MFMA C/D frag

__device__ __forceinline__ u16 f2h(float f) {
  _Float16 h = (_Float16)f;
  return __builtin_bit_cast(unsigned short, h);
}
__device__ __forceinline__ float h2f(u16 u) {
  _Float16 h = __builtin_bit_cast(_Float16, u);
  return (float)h;
}

// ---- scan_state (once, fully parallel): kh_all = fp16(k[:, i]) for all i,
//      m_kh_all[i] = m_k EMA (fp16 state, fp32 math), pv0 = v[:,0], m_v0 = 0,
//      gt = v[:,1:].  ILP-4: four independent chunk chains per thread; all
//      4 chains' loads issue before any EMA math (memory-level parallelism). ----
__global__ __launch_bounds__(256) void scan_state(
    const float* __restrict__ k, const float* __restrict__ v,
    const float* __restrict__ att,
    u16* __restrict__ kh_all, u16* __restrict__ m_kh_all,
    float* __restrict__ pv0, float* __restrict__ mv0,
    float* __restrict__ out)
{
  long idx = (long)blockIdx.x * 256 + threadIdx.x;
  long stride = (long)gridDim.x * 256;
  const long N4 = (long)BS * HW * 32 / 4;      // 65,536 chain quads
  const long SSTR = (long)HW * CK;             // per-step element stride
  for (long t = idx; t < N4; t += stride) {
    const float* kp[4]; u16* khp[4]; u16* mkp[4]; const float* ap[4];
    u16 mh[4][8];
    #pragma unroll
    for (int c = 0; c < 4; ++c) {
      long ci = t + (long)c * N4;
      long b = ci >> 15, ra = ci & 32767, p = ra >> 5, s = ra & 31;
      kp[c]  = k + ((long)b * SEQ * HW + p) * CK + s * 8;
      khp[c] = kh_all + ((long)b * SEQ * HW + p) * CK + s * 8;
      mkp[c] = m_kh_all + ((long)b * STEPS * HW + p) * CK + s * 8;
      ap[c]  = att + (long)b * SEQ * HW + p;
      #pragma unroll
      for (int j = 0; j < 8; ++j) mh[c][j] = 0;
    }
    for (int i = 0; i < SEQ; ++i) {
      float4 lo[4], hi[4];
      #pragma unroll
      for (int c = 0; c < 4; ++c) {           // 8 loads in flight (256B/lane)
        lo[c] = *(const float4*)(kp[c] + (long)i * SSTR);
        hi[c] = *(const float4*)(kp[c] + (long)i * SSTR + 4);
      }
      float av[4];
      if (i < STEPS) {
        #pragma unroll
        for (int c = 0; c < 4; ++c) av[c] = ap[c][(long)i * HW];
      }
      #pragma unroll
      for (int c = 0; c < 4; ++c) {
        float kf[8] = {lo[c].x, lo[c].y, lo[c].z, lo[c].w,
                       hi[c].x, hi[c].y, hi[c].z, hi[c].w};
        u16 h8[8];
        #pragma unroll
        for (int j = 0; j < 8; ++j) h8[j] = f2h(kf[j]);
        *(int4*)(khp[c] + (long)i * SSTR) = *(const int4*)h8;
        if (i < STEPS) {
          float g = 1.0f / (1.0f + __expf(-av[c])), og = 1.0f - g;
          #pragma unroll
          for (int j = 0; j < 8; ++j)
            mh[c][j] = f2h(fmaf(g, kf[j], og * h2f(mh[c][j])));
          *(int4*)(mkp[c] + (long)i * SSTR) = *(const int4*)mh[c];
        }
      }
    }
  }
  // pv0 = v[:,0], m_v0 = 0
  const long NV = (long)BS * HW * CV;
  for (long t = idx; t < NV; t += stride) {
    long b = t / (HW * CV), r = t - b * (HW * CV);
    pv0[t] = v[(long)b * SEQ * HW * CV + r];
    mv0[t] = 0.0f;
  }
  // gt = v[:,1:]
  const long NG = (long)BS * STEPS * HW * CV;
  for (long t = idx; t < NG; t += stride) {
    long b = t / (STEPS * HW * CV), r = t - b * (STEPS * HW * CV);
    long i = r / (HW * CV), rr = r - i * (HW * CV);
    out[NG + t] = v[((long)b * SEQ + i + 1) * (HW * CV) + rr];
  }
}

// --------- per-step fused dual-attention: barrier-free wave-autonomous ---------
// grid (BS, 32): block = (batch, 32 q-rows), 1024 thr = 16 waves = 4/SIMD.
// Wave (w2 = w>>1, qi = w&1): p-range [w2*128, (w2+1)*128), q-half qi.
// MFMA: A = p-rows (streamed), B = q-tile half (regs, 32 VGPR). D[p][q]:
// lane q-col = lane&15, p-rows = (lane>>4)*4+reg -> online softmax in-register.
// m_v EMA fused: each block recomputes m_v_i into LDS; block y==0 publishes.
__global__ __launch_bounds__(1024, 1) void attn_step(
    const u16* __restrict__ kh_all, const u16* __restrict__ m_kh_all,
    const float* __restrict__ v, const int* __restrict__ seq_mask,
    const float* __restrict__ att,
    const float* __restrict__ mv_in, float* __restrict__ mv_out,
    const float* __restrict__ pv_in, float* __restrict__ pv_out,
    float* __restrict__ out, int step)
{
  __shared__ u16 Kq[32 * SKP];          // q-tile fp16 (16.9 KB)
  __shared__ float Vp[HW * CV];         // prev_v staged (12 KB)
  __shared__ float Vm[HW * CV];         // m_v (updated) staged (12 KB)
  __shared__ float Mg[8][2][32][5];     // per-p-chunk partial states (10.2 KB)

  const int b = blockIdx.x;
  const int q0 = blockIdx.y * 32;
  const int tid = threadIdx.x;
  const int w = tid >> 6, lane = tid & 63;
  const int w2 = w >> 1, qi = w & 1;
  const int r = lane & 15, rg = lane >> 4;

  const u16* Kn = kh_all + (long)(b * SEQ + step + 1) * HW * CK;  // q side
  const u16* Kc = kh_all + (long)(b * SEQ + step) * HW * CK;      // p side
  const u16* Mb = m_kh_all + (long)(b * STEPS + step) * HW * CK;  // p side

  { // stage q-tile: 1024 16B-chunks over 1024 threads
    int row = tid >> 5, off = (tid & 31) * 8;
    *(int4*)&Kq[row * SKP + off] = *(const int4*)(Kn + (long)(q0 + row) * CK + off);
  }
  { // stage V values + fused m_v EMA: m_v_i = g*pv_i + (1-g)*m_v_{i-1}
    const float* ar = att + (long)(b * SEQ + step) * HW;
    int row = tid;
    float a = ar[row];
    float g = 1.0f / (1.0f + __expf(-a));
    float og = 1.0f - g;
    long base = (long)(b * HW + row) * CV;
    #pragma unroll
    for (int c = 0; c < CV; ++c) {
      float pv = pv_in[base + c];
      float mv = fmaf(g, pv, og * mv_in[base + c]);
      Vp[row * CV + c] = pv;
      Vm[row * CV + c] = mv;
      if (blockIdx.y == 0) mv_out[base + c] = mv;
    }
  }
  __syncthreads();

  // B fragments: this wave's q-half, 8 k-steps (32 VGPR)
  half8 Bq[8];
  #pragma unroll
  for (int kk = 0; kk < 8; ++kk)
    Bq[kk] = *(const half8*)&Kq[(qi * 16 + r) * SKP + kk * 32 + rg * 8];

  // online state per mat: q-col = qi*16 + r, p-subset = this lane's rows
  float mx[2], l[2], acc[2][3];
  #pragma unroll
  for (int m = 0; m < 2; ++m) {
    mx[m] = -1e30f; l[m] = 0.f;
    acc[m][0] = acc[m][1] = acc[m][2] = 0.f;
  }

  for (int pc = 0; pc < 4; ++pc) {
    const int p0 = w2 * 128 + pc * 32;
    #pragma unroll
    for (int mat = 0; mat < 2; ++mat) {
      const u16* Ab = mat ? Mb : Kc;
      const float* Vb = mat ? Vm : Vp;
      #pragma unroll
      for (int pi = 0; pi < 2; ++pi) {
        const int pr = p0 + pi * 16;
        // V values for this lane's 4 p-rows, from LDS (broadcast within rg group)
        float Vv[4][3];
        #pragma unroll
        for (int j = 0; j < 4; ++j) {
          const float* vp = Vb + (pr + rg * 4 + j) * CV;
          Vv[j][0] = vp[0]; Vv[j][1] = vp[1]; Vv[j][2] = vp[2];
        }
        // A fragments: 16 p-rows x 32-k per kk step
        half8 A[8];
        #pragma unroll
        for (int kk = 0; kk < 8; ++kk)
          A[kk] = *(const half8*)(Ab + (long)(pr + r) * CK + kk * 32 + rg * 8);
        floatx4 cc = {0.f, 0.f, 0.f, 0.f};
        #pragma unroll
        for (int kk = 0; kk < 8; ++kk)
          cc = __builtin_amdgcn_mfma_f32_16x16x32_f16(A[kk], Bq[kk], cc, 0, 0, 0);
        // absorb 4 p-values into online state
        float tmax = fmaxf(fmaxf(cc[0], cc[1]), fmaxf(cc[2], cc[3]));
        tmax = fmaxf(tmax, mx[mat]);
        float sc = __expf(mx[mat] - tmax);
        l[mat] *= sc;
        acc[mat][0] *= sc; acc[mat][1] *= sc; acc[mat][2] *= sc;
        #pragma unroll
        for (int j = 0; j < 4; ++j) {
          float e = __expf(cc[j] - tmax);
          l[mat] += e;
          acc[mat][0] = fmaf(e, Vv[j][0], acc[mat][0]);
          acc[mat][1] = fmaf(e, Vv[j][1], acc[mat][1]);
          acc[mat][2] = fmaf(e, Vv[j][2], acc[mat][2]);
        }
        mx[mat] = tmax;
      }
    }
  }

  // merge the 4 rowgroup partials (lanes r, r+16, r+32, r+48) via shuffle
  #pragma unroll
  for (int off = 16; off <= 32; off <<= 1) {
    #pragma unroll
    for (int m = 0; m < 2; ++m) {
      float m2 = __shfl_xor(mx[m], off);
      float l2 = __shfl_xor(l[m], off);
      float b0s = __shfl_xor(acc[m][0], off);
      float b1s = __shfl_xor(acc[m][1], off);
      float b2s = __shfl_xor(acc[m][2], off);
      float mn = fmaxf(mx[m], m2);
      float e1 = __expf(mx[m] - mn), e2 = __expf(m2 - mn);
      l[m] = l[m] * e1 + l2 * e2;
      acc[m][0] = acc[m][0] * e1 + b0s * e2;
      acc[m][1] = acc[m][1] * e1 + b1s * e2;
      acc[m][2] = acc[m][2] * e1 + b2s * e2;
      mx[m] = mn;
    }
  }
  if (rg == 0) {
    #pragma unroll
    for (int m = 0; m < 2; ++m) {
      float* d = Mg[w2][m][qi * 16 + r];
      d[0] = mx[m]; d[1] = l[m];
      d[2] = acc[m][0]; d[3] = acc[m][1]; d[4] = acc[m][2];
    }
  }
  __syncthreads();

  // final cross-chunk merge + output: one thread per q-row
  if (tid < 32) {
    const int q = tid;
    float res[2][3];
    #pragma unroll
    for (int m = 0; m < 2; ++m) {
      float M = -1e30f, L = 0.f, A0 = 0.f, A1 = 0.f, A2 = 0.f;
      #pragma unroll
      for (int ww = 0; ww < 8; ++ww) {
        const float* d = Mg[ww][m][q];
        float mn = fmaxf(M, d[0]);
        float e1 = __expf(M - mn), e2 = __expf(d[0] - mn);
        L = L * e1 + d[1] * e2;
        A0 = A0 * e1 + d[2] * e2;
        A1 = A1 * e1 + d[3] * e2;
        A2 = A2 * e1 + d[4] * e2;
        M = mn;
      }
      float iL = 1.0f / L;
      res[m][0] = A0 * iL; res[m][1] = A1 * iL; res[m][2] = A2 * iL;
    }
    const int maskv = seq_mask[b * SEQ + step];
    const int qg = q0 + q;
    float* ov = out + ((long)(b * STEPS + step) * HW + qg) * CV;
    float* po = pv_out + ((long)(b * HW + qg)) * CV;
    const float* vr = v + ((long)(b * SEQ + step) * HW + qg) * CV;
    #pragma unroll
    for (int c = 0; c < CV; ++c) {
      float rec = 0.9f * res[0][c] + 0.1f * res[1][c];  // COEF_MEMORY = 0.1
      ov[c] = rec;
      po[c] = maskv ? vr[c] : rec;
    }
  }
}

extern "C" void kernel_launch(void* const* d_in, const int* in_sizes, int n_in,
                              void* d_out, int out_size, void* d_ws, size_t ws_size,
                              hipStream_t stream) {
  const float* k   = (const float*)d_in[0];
  const float* v   = (const float*)d_in[1];
  const float* att = (const float*)d_in[2];
  const int* seq_mask = (const int*)d_in[3];
  float* out = (float*)d_out;
  char* ws = (char*)d_ws;

  // workspace layout (~130.4 MB of the 512 MiB ws):
  // kh_all 67,108,864 | m_kh_all 62,914,560 | pvA,pvB,mvA,mvB 4x98,304
  const size_t KH_ALL  = (size_t)BS * SEQ * HW * CK * 2;
  const size_t MKH_ALL = (size_t)BS * STEPS * HW * CK * 2;
  const size_t SV      = (size_t)BS * HW * CV * 4;

  u16*   kh_all   = (u16*)(ws);
  u16*   m_kh_all = (u16*)(ws + KH_ALL);
  float* pvA      = (float*)(ws + KH_ALL + MKH_ALL);
  float* pvB      = (float*)(ws + KH_ALL + MKH_ALL + SV);
  float* mvA      = (float*)(ws + KH_ALL + MKH_ALL + 2 * SV);
  float* mvB      = (float*)(ws + KH_ALL + MKH_ALL + 3 * SV);

  // one parallel kernel: all conversions + m_k scan + pv0/mv0 init + gt copy
  scan_state<<<256, 256, 0, stream>>>(k, v, att, kh_all, m_kh_all, pvA, mvA, out);

  // serial chain: 15 attention steps only
  for (int i = 0; i < STEPS; ++i) {
    float* pin  = (i & 1) ? pvB : pvA;
    float* pout = (i & 1) ? pvA : pvB;
    float* mvi  = (i & 1) ? mvB : mvA;
    float* mvo  = (i & 1) ? mvA : mvB;
    attn_step<<<dim3(BS, 32), 1024, 0, stream>>>(kh_all, m_kh_all, v, seq_mask,
                                                 att, mvi, mvo, pin, pout, out, i);
  }
}